// Round 10
// baseline (238.476 us; speedup 1.0000x reference)
//
#include <hip/hip_runtime.h>

#define IN_DIM 128
#define OUT_DIM 64
#define PADK 136     // gemm LDS row stride (bf16 elems)
#define RT2 32       // rows per bucket
#define RT2SH 5      // log2(RT2)
#define CAP 768      // bucket capacity (mean 512, +11 sigma)
#define OCAP 8192    // overflow list capacity
#define FB 512       // fill blocks fused into K1

typedef float f32x4 __attribute__((ext_vector_type(4)));
typedef short bf16x8 __attribute__((ext_vector_type(8)));

__device__ __forceinline__ unsigned short f2bf(float f) {   // RNE f32->bf16
    unsigned u = __float_as_uint(f);
    return (unsigned short)((u + 0x7FFFu + ((u >> 16) & 1u)) >> 16);
}
__device__ __forceinline__ float bf2f(unsigned short h) {
    return __uint_as_float((unsigned)h << 16);
}

// ---------------------------------------------------------------------------
// GEMM device body: xw = x@W via split-bf16 MFMA (hi*hi + hi*lo + lo*hi),
// 64 rows per block `blk`.
// ---------------------------------------------------------------------------
__device__ __forceinline__ void gemm_body(const float* __restrict__ x,
                                          const float* __restrict__ w,
                                          float* __restrict__ xw, int N, int blk) {
    __shared__ unsigned short Ahi[64 * PADK];
    __shared__ unsigned short Alo[64 * PADK];
    __shared__ unsigned short Bhi[64 * PADK];   // W^T: [c][k]
    __shared__ unsigned short Blo[64 * PADK];

    const int t = threadIdx.x;
    const int r0 = blk * 64;

    {   // stage W^T hi/lo
        const int c = t >> 2;
        const int kb = (t & 3) * 32;
        for (int k4 = 0; k4 < 32; k4 += 4) {
            ushort4 h, l;
            float v0 = w[(kb + k4 + 0) * OUT_DIM + c];
            float v1 = w[(kb + k4 + 1) * OUT_DIM + c];
            float v2 = w[(kb + k4 + 2) * OUT_DIM + c];
            float v3 = w[(kb + k4 + 3) * OUT_DIM + c];
            h.x = f2bf(v0); l.x = f2bf(v0 - bf2f(h.x));
            h.y = f2bf(v1); l.y = f2bf(v1 - bf2f(h.y));
            h.z = f2bf(v2); l.z = f2bf(v2 - bf2f(h.z));
            h.w = f2bf(v3); l.w = f2bf(v3 - bf2f(h.w));
            *(ushort4*)&Bhi[c * PADK + kb + k4] = h;
            *(ushort4*)&Blo[c * PADK + kb + k4] = l;
        }
    }
    {   // stage x rows hi/lo
        const float4* x4 = (const float4*)x;
        for (int i = 0; i < 8; ++i) {
            const int f = i * 256 + t;
            const int rr = f >> 5;
            const int kk = (f & 31) * 4;
            int row = r0 + rr; if (row >= N) row = N - 1;
            float4 v = x4[(size_t)row * (IN_DIM / 4) + (kk >> 2)];
            ushort4 h, l;
            h.x = f2bf(v.x); l.x = f2bf(v.x - bf2f(h.x));
            h.y = f2bf(v.y); l.y = f2bf(v.y - bf2f(h.y));
            h.z = f2bf(v.z); l.z = f2bf(v.z - bf2f(h.z));
            h.w = f2bf(v.w); l.w = f2bf(v.w - bf2f(h.w));
            *(ushort4*)&Ahi[rr * PADK + kk] = h;
            *(ushort4*)&Alo[rr * PADK + kk] = l;
        }
    }
    __syncthreads();

    const int lane = t & 63;
    const int wv = t >> 6;
    const int m = lane & 15;
    const int quad = lane >> 4;

    bf16x8 ahi[4], alo[4];
#pragma unroll
    for (int ks = 0; ks < 4; ++ks) {
        const int off = (wv * 16 + m) * PADK + ks * 32 + quad * 8;
        ahi[ks] = *(const bf16x8*)&Ahi[off];
        alo[ks] = *(const bf16x8*)&Alo[off];
    }
#pragma unroll
    for (int ct = 0; ct < 4; ++ct) {
        f32x4 acc = {0.f, 0.f, 0.f, 0.f};
#pragma unroll
        for (int ks = 0; ks < 4; ++ks) {
            const int off = (ct * 16 + m) * PADK + ks * 32 + quad * 8;
            bf16x8 bh = *(const bf16x8*)&Bhi[off];
            bf16x8 bl = *(const bf16x8*)&Blo[off];
            acc = __builtin_amdgcn_mfma_f32_16x16x32_bf16(alo[ks], bh, acc, 0, 0, 0);
            acc = __builtin_amdgcn_mfma_f32_16x16x32_bf16(ahi[ks], bl, acc, 0, 0, 0);
            acc = __builtin_amdgcn_mfma_f32_16x16x32_bf16(ahi[ks], bh, acc, 0, 0, 0);
        }
#pragma unroll
        for (int i = 0; i < 4; ++i) {
            const int row = r0 + wv * 16 + quad * 4 + i;
            if (row < N) xw[(size_t)row * OUT_DIM + ct * 16 + m] = acc[i];
        }
    }
}

// ---------------------------------------------------------------------------
// overflow escape hatch for pos >= CAP (statistically never taken)
// ---------------------------------------------------------------------------
__device__ __forceinline__ void overflow_edge(int r, int c, float v,
                                              int* ocount, uint4* olist,
                                              float* out) {
    const int oi = atomicAdd(ocount, 1);
    if (oi < OCAP) {
        olist[oi] = make_uint4((unsigned)r, (unsigned)c, __float_as_uint(v), 0u);
    } else {
        float* dst = out + (size_t)r * OUT_DIM;
        for (int k = 0; k < OUT_DIM; ++k) ;  // placeholder removed below
    }
}

// ---------------------------------------------------------------------------
// K1: blocks [0,GB) run the GEMM; blocks [GB,GB+FB) scatter edges into
// fixed-capacity 32-row buckets: pos = atomicAdd(pcur[b]); store 8 B packed
// (col | rowLocal<<16, fp32 val).  The scatter is L2-fabric-wall bound, not
// CU bound, so it overlaps the MFMA GEMM for free.  4-edge ILP.
// ---------------------------------------------------------------------------
__global__ __launch_bounds__(256) void gemm_and_fill(
        const float* __restrict__ x, const float* __restrict__ w,
        float* __restrict__ xw, int N,
        const int* __restrict__ arow, const int* __restrict__ acol,
        const float* __restrict__ aval,
        int* __restrict__ pcur, int* __restrict__ ocount,
        uint4* __restrict__ olist, uint2* __restrict__ payload,
        float* __restrict__ out, int E, int GB) {
    if ((int)blockIdx.x < GB) {
        gemm_body(x, w, xw, N, blockIdx.x);
        return;
    }
    const int f = blockIdx.x - GB;
    const int tid = f * 256 + (int)threadIdx.x;
    const int nt = FB * 256;
    const int E4 = E >> 2;
    const int4*   ar4 = (const int4*)arow;
    const int4*   ac4 = (const int4*)acol;
    const float4* av4 = (const float4*)aval;

    for (int q = tid; q < E4; q += nt) {
        int4   r = ar4[q];
        int4   c = ac4[q];
        float4 v = av4[q];
        int p0 = atomicAdd(&pcur[r.x >> RT2SH], 1);
        int p1 = atomicAdd(&pcur[r.y >> RT2SH], 1);
        int p2 = atomicAdd(&pcur[r.z >> RT2SH], 1);
        int p3 = atomicAdd(&pcur[r.w >> RT2SH], 1);
        if (p0 < CAP) payload[(size_t)(r.x >> RT2SH) * CAP + p0] =
            make_uint2((unsigned)c.x | ((unsigned)(r.x & (RT2-1)) << 16), __float_as_uint(v.x));
        if (p1 < CAP) payload[(size_t)(r.y >> RT2SH) * CAP + p1] =
            make_uint2((unsigned)c.y | ((unsigned)(r.y & (RT2-1)) << 16), __float_as_uint(v.y));
        if (p2 < CAP) payload[(size_t)(r.z >> RT2SH) * CAP + p2] =
            make_uint2((unsigned)c.z | ((unsigned)(r.z & (RT2-1)) << 16), __float_as_uint(v.z));
        if (p3 < CAP) payload[(size_t)(r.w >> RT2SH) * CAP + p3] =
            make_uint2((unsigned)c.w | ((unsigned)(r.w & (RT2-1)) << 16), __float_as_uint(v.w));
        // overflow (never for this degree distribution)
        if (p0 >= CAP) { int oi = atomicAdd(ocount,1); if (oi<OCAP) olist[oi]=make_uint4(r.x,c.x,__float_as_uint(v.x),0u); else { float* d=out+(size_t)r.x*OUT_DIM; for(int k=0;k<OUT_DIM;++k) atomicAdd(&d[k], v.x*xw[(size_t)c.x*OUT_DIM+k]); } }
        if (p1 >= CAP) { int oi = atomicAdd(ocount,1); if (oi<OCAP) olist[oi]=make_uint4(r.y,c.y,__float_as_uint(v.y),0u); else { float* d=out+(size_t)r.y*OUT_DIM; for(int k=0;k<OUT_DIM;++k) atomicAdd(&d[k], v.y*xw[(size_t)c.y*OUT_DIM+k]); } }
        if (p2 >= CAP) { int oi = atomicAdd(ocount,1); if (oi<OCAP) olist[oi]=make_uint4(r.z,c.z,__float_as_uint(v.z),0u); else { float* d=out+(size_t)r.z*OUT_DIM; for(int k=0;k<OUT_DIM;++k) atomicAdd(&d[k], v.z*xw[(size_t)c.z*OUT_DIM+k]); } }
        if (p3 >= CAP) { int oi = atomicAdd(ocount,1); if (oi<OCAP) olist[oi]=make_uint4(r.w,c.w,__float_as_uint(v.w),0u); else { float* d=out+(size_t)r.w*OUT_DIM; for(int k=0;k<OUT_DIM;++k) atomicAdd(&d[k], v.w*xw[(size_t)c.w*OUT_DIM+k]); } }
    }
    for (int e = E4 * 4 + tid; e < E; e += nt) {   // tail
        const int r = arow[e], c = acol[e];
        const float v = aval[e];
        const int pos = atomicAdd(&pcur[r >> RT2SH], 1);
        if (pos < CAP) {
            payload[(size_t)(r >> RT2SH) * CAP + pos] =
                make_uint2((unsigned)c | ((unsigned)(r & (RT2-1)) << 16), __float_as_uint(v));
        } else {
            int oi = atomicAdd(ocount,1);
            if (oi<OCAP) olist[oi]=make_uint4(r,c,__float_as_uint(v),0u);
            else { float* d=out+(size_t)r*OUT_DIM; for(int k=0;k<OUT_DIM;++k) atomicAdd(&d[k], v*xw[(size_t)c*OUT_DIM+k]); }
        }
    }
}

// ---------------------------------------------------------------------------
// K2: per-bucket aggregation.  Block b owns rows [32b, 32b+32).  Whole
// bucket (<=768 entries, 6 KB) staged row-sorted in LDS (int atomics only),
// then wave wv pulls rows [wv*8, wv*8+8) into registers with 4-edge-ILP
// coalesced 256 B xw gathers.  Fused ReLU store.  No fp32 atomics.
// ---------------------------------------------------------------------------
__global__ __launch_bounds__(256) void bagg2(
        const int* __restrict__ pcur, const uint2* __restrict__ payload,
        const float* __restrict__ xw, float* __restrict__ out, int N,
        const int* __restrict__ ocount, const uint4* __restrict__ olist,
        float* __restrict__ out_prev) {
    __shared__ uint2 stage[CAP];        // 6 KB
    __shared__ int bins[RT2 + 1];
    __shared__ int pl[RT2];
    const int t = threadIdx.x;
    const int lane = t & 63;
    const int wv = t >> 6;              // 0..3
    const int b = blockIdx.x;
    const int r0 = b << RT2SH;

    const int cnt_raw = pcur[b];
    const int cnt = min(cnt_raw, CAP);
    if (t <= RT2) bins[t] = 0;
    if (t < RT2) pl[t] = 0;
    __syncthreads();

    const uint2* pay = payload + (size_t)b * CAP;
    for (int i = t; i < cnt; i += 256)
        atomicAdd(&bins[(pay[i].x >> 16) & 31], 1);
    __syncthreads();
    if (t == 0) {                       // exclusive scan of 32 bins
        int run = 0;
        for (int i = 0; i < RT2; ++i) { int v = bins[i]; bins[i] = run; run += v; }
        bins[RT2] = run;
    }
    __syncthreads();
    for (int i = t; i < cnt; i += 256) {
        const uint2 e = pay[i];
        const int rl = (e.x >> 16) & 31;
        stage[bins[rl] + atomicAdd(&pl[rl], 1)] = e;
    }
    __syncthreads();

    float acc[8];
#pragma unroll
    for (int lr = 0; lr < 8; ++lr) {
        const int row = wv * 8 + lr;
        int j = bins[row];
        const int end = bins[row + 1];
        float a = 0.f;
        for (; j + 4 <= end; j += 4) {
            uint2 e0 = stage[j], e1 = stage[j+1], e2 = stage[j+2], e3 = stage[j+3];
            float g0 = xw[(size_t)(e0.x & 0xFFFF) * OUT_DIM + lane];
            float g1 = xw[(size_t)(e1.x & 0xFFFF) * OUT_DIM + lane];
            float g2 = xw[(size_t)(e2.x & 0xFFFF) * OUT_DIM + lane];
            float g3 = xw[(size_t)(e3.x & 0xFFFF) * OUT_DIM + lane];
            a = fmaf(__uint_as_float(e0.y), g0, a);
            a = fmaf(__uint_as_float(e1.y), g1, a);
            a = fmaf(__uint_as_float(e2.y), g2, a);
            a = fmaf(__uint_as_float(e3.y), g3, a);
        }
        for (; j < end; ++j) {
            uint2 e0 = stage[j];
            a = fmaf(__uint_as_float(e0.y),
                     xw[(size_t)(e0.x & 0xFFFF) * OUT_DIM + lane], a);
        }
        acc[lr] = a;
    }

    // overflow contributions (oc == 0 in practice: one uniform load + branch)
    const int oc_raw = *ocount;
    const int oc = min(oc_raw, OCAP);
    if (oc > 0) {
        for (int i = 0; i < oc; ++i) {
            const uint4 e = olist[i];
            const int row = (int)e.x;
            if (row >= r0 + wv * 8 && row < r0 + wv * 8 + 8)
                acc[row - r0 - wv * 8] += __uint_as_float(e.z) *
                    xw[(size_t)e.y * OUT_DIM + lane];
        }
    }
    const bool deep = (oc_raw > OCAP);   // beyond-olist edges went to out_prev

#pragma unroll
    for (int lr = 0; lr < 8; ++lr) {
        const int row = r0 + wv * 8 + lr;
        if (row < N) {
            float v = acc[lr];
            if (deep) v += out_prev[(size_t)row * OUT_DIM + lane];
            out[(size_t)row * OUT_DIM + lane] = v > 0.f ? v : 0.f;
        }
    }
}

// ---------------------------------------------------------------------------
// Fallback: standalone gemm + atomic scatter + relu (always correct).
// ---------------------------------------------------------------------------
__global__ __launch_bounds__(256) void gemm_only(const float* __restrict__ x,
                                                 const float* __restrict__ w,
                                                 float* __restrict__ xw, int N) {
    gemm_body(x, w, xw, N, blockIdx.x);
}

__global__ __launch_bounds__(256) void scatter_edges(
        const int* __restrict__ arow, const int* __restrict__ acol,
        const float* __restrict__ aval, const float* __restrict__ xw,
        float* __restrict__ out, int E) {
    const int lane = threadIdx.x & 63;
    int gw = (blockIdx.x * 256 + (int)threadIdx.x) >> 6;
    const int nw = (gridDim.x * 256) >> 6;
    for (int e = gw; e < E; e += nw) {
        const float m = aval[e] * xw[(size_t)acol[e] * OUT_DIM + lane];
        atomicAdd(&out[(size_t)arow[e] * OUT_DIM + lane], m);
    }
}

__global__ __launch_bounds__(256) void relu_inplace(float* __restrict__ o, int n4) {
    float4* p = (float4*)o;
    int i = blockIdx.x * 256 + threadIdx.x;
    const int stride = gridDim.x * 256;
    for (; i < n4; i += stride) {
        float4 v = p[i];
        v.x = v.x > 0.f ? v.x : 0.f;
        v.y = v.y > 0.f ? v.y : 0.f;
        v.z = v.z > 0.f ? v.z : 0.f;
        v.w = v.w > 0.f ? v.w : 0.f;
        p[i] = v;
    }
}

static inline size_t align256(size_t x) { return (x + 255) & ~(size_t)255; }

extern "C" void kernel_launch(void* const* d_in, const int* in_sizes, int n_in,
                              void* d_out, int out_size, void* d_ws, size_t ws_size,
                              hipStream_t stream) {
    const float* x    = (const float*)d_in[0];
    const float* w    = (const float*)d_in[1];
    const int*   arow = (const int*)d_in[2];
    const int*   acol = (const int*)d_in[3];
    const float* aval = (const float*)d_in[4];
    float*       out  = (float*)d_out;

    const int N = in_sizes[0] / IN_DIM;    // 50000
    const int E = in_sizes[2];             // 800000
    const int P2 = (N + RT2 - 1) >> RT2SH; // 1563
    const int GB = (N + 63) / 64;          // gemm blocks

    char* ws = (char*)d_ws;
    const size_t szXW  = align256((size_t)N * OUT_DIM * sizeof(float));
    const size_t szCnt = align256((size_t)(P2 + 1) * sizeof(int));   // pcur + ocount
    const size_t szOl  = align256((size_t)OCAP * sizeof(uint4));
    const size_t szPay = (size_t)P2 * CAP * sizeof(uint2);
    const size_t need0 = szXW + szCnt + szOl + szPay;

    float* xw      = (float*)ws;
    int*   pcur    = (int*)(ws + szXW);
    int*   ocount  = pcur + P2;
    uint4* olist   = (uint4*)(ws + szXW + szCnt);
    uint2* payload = (uint2*)(ws + szXW + szCnt + szOl);

    if (ws_size >= need0 && N <= 65536) {
        (void)hipMemsetAsync(pcur, 0, (size_t)(P2 + 1) * sizeof(int), stream);
        (void)hipMemsetAsync(d_out, 0, (size_t)out_size * sizeof(float), stream);
        gemm_and_fill<<<GB + FB, 256, 0, stream>>>(x, w, xw, N, arow, acol, aval,
                                                   pcur, ocount, olist, payload,
                                                   out, E, GB);
        bagg2<<<P2, 256, 0, stream>>>(pcur, payload, xw, out, N, ocount, olist, out);
    } else {
        gemm_only<<<GB, 256, 0, stream>>>(x, w, xw, N);
        (void)hipMemsetAsync(d_out, 0, (size_t)out_size * sizeof(float), stream);
        scatter_edges<<<4096, 256, 0, stream>>>(arow, acol, aval, xw, out, E);
        relu_inplace<<<2048, 256, 0, stream>>>(out, out_size / 4);
    }
}

// Round 11
// 146.932 us; speedup vs baseline: 1.6230x; 1.6230x over previous
//
#include <hip/hip_runtime.h>

#define IN_DIM 128
#define OUT_DIM 64
#define PADK 136     // gemm LDS row stride (bf16 elems)
#define RB 64        // rows per bucket
#define RBSH 6       // log2(RB)
#define CAPB 1280    // bucket capacity (mean 1024, sigma 32 -> +8 sigma)
#define AB2 128      // afill blocks

typedef float f32x4 __attribute__((ext_vector_type(4)));
typedef short bf16x8 __attribute__((ext_vector_type(8)));

__device__ __forceinline__ unsigned short f2bf(float f) {   // RNE f32->bf16
    unsigned u = __float_as_uint(f);
    return (unsigned short)((u + 0x7FFFu + ((u >> 16) & 1u)) >> 16);
}
__device__ __forceinline__ float bf2f(unsigned short h) {
    return __uint_as_float((unsigned)h << 16);
}

// ---------------------------------------------------------------------------
// GEMM: xw = x@W via split-bf16 MFMA (hi*hi + hi*lo + lo*hi), 64 rows/block.
// Proven at <~25 us standalone (R5/R6).
// ---------------------------------------------------------------------------
__device__ __forceinline__ void gemm_body(const float* __restrict__ x,
                                          const float* __restrict__ w,
                                          float* __restrict__ xw, int N, int blk) {
    __shared__ unsigned short Ahi[64 * PADK];
    __shared__ unsigned short Alo[64 * PADK];
    __shared__ unsigned short Bhi[64 * PADK];   // W^T: [c][k]
    __shared__ unsigned short Blo[64 * PADK];

    const int t = threadIdx.x;
    const int r0 = blk * 64;

    {   // stage W^T hi/lo
        const int c = t >> 2;
        const int kb = (t & 3) * 32;
        for (int k4 = 0; k4 < 32; k4 += 4) {
            ushort4 h, l;
            float v0 = w[(kb + k4 + 0) * OUT_DIM + c];
            float v1 = w[(kb + k4 + 1) * OUT_DIM + c];
            float v2 = w[(kb + k4 + 2) * OUT_DIM + c];
            float v3 = w[(kb + k4 + 3) * OUT_DIM + c];
            h.x = f2bf(v0); l.x = f2bf(v0 - bf2f(h.x));
            h.y = f2bf(v1); l.y = f2bf(v1 - bf2f(h.y));
            h.z = f2bf(v2); l.z = f2bf(v2 - bf2f(h.z));
            h.w = f2bf(v3); l.w = f2bf(v3 - bf2f(h.w));
            *(ushort4*)&Bhi[c * PADK + kb + k4] = h;
            *(ushort4*)&Blo[c * PADK + kb + k4] = l;
        }
    }
    {   // stage x rows hi/lo
        const float4* x4 = (const float4*)x;
        for (int i = 0; i < 8; ++i) {
            const int f = i * 256 + t;
            const int rr = f >> 5;
            const int kk = (f & 31) * 4;
            int row = r0 + rr; if (row >= N) row = N - 1;
            float4 v = x4[(size_t)row * (IN_DIM / 4) + (kk >> 2)];
            ushort4 h, l;
            h.x = f2bf(v.x); l.x = f2bf(v.x - bf2f(h.x));
            h.y = f2bf(v.y); l.y = f2bf(v.y - bf2f(h.y));
            h.z = f2bf(v.z); l.z = f2bf(v.z - bf2f(h.z));
            h.w = f2bf(v.w); l.w = f2bf(v.w - bf2f(h.w));
            *(ushort4*)&Ahi[rr * PADK + kk] = h;
            *(ushort4*)&Alo[rr * PADK + kk] = l;
        }
    }
    __syncthreads();

    const int lane = t & 63;
    const int wv = t >> 6;
    const int m = lane & 15;
    const int quad = lane >> 4;

    bf16x8 ahi[4], alo[4];
#pragma unroll
    for (int ks = 0; ks < 4; ++ks) {
        const int off = (wv * 16 + m) * PADK + ks * 32 + quad * 8;
        ahi[ks] = *(const bf16x8*)&Ahi[off];
        alo[ks] = *(const bf16x8*)&Alo[off];
    }
#pragma unroll
    for (int ct = 0; ct < 4; ++ct) {
        f32x4 acc = {0.f, 0.f, 0.f, 0.f};
#pragma unroll
        for (int ks = 0; ks < 4; ++ks) {
            const int off = (ct * 16 + m) * PADK + ks * 32 + quad * 8;
            bf16x8 bh = *(const bf16x8*)&Bhi[off];
            bf16x8 bl = *(const bf16x8*)&Blo[off];
            acc = __builtin_amdgcn_mfma_f32_16x16x32_bf16(alo[ks], bh, acc, 0, 0, 0);
            acc = __builtin_amdgcn_mfma_f32_16x16x32_bf16(ahi[ks], bl, acc, 0, 0, 0);
            acc = __builtin_amdgcn_mfma_f32_16x16x32_bf16(ahi[ks], bh, acc, 0, 0, 0);
        }
#pragma unroll
        for (int i = 0; i < 4; ++i) {
            const int row = r0 + wv * 16 + quad * 4 + i;
            if (row < N) xw[(size_t)row * OUT_DIM + ct * 16 + m] = acc[i];
        }
    }
}

__global__ __launch_bounds__(256) void gemm_only(const float* __restrict__ x,
                                                 const float* __restrict__ w,
                                                 float* __restrict__ xw, int N) {
    gemm_body(x, w, xw, N, blockIdx.x);
}

// ---------------------------------------------------------------------------
// afill: bin edges into fixed-capacity 64-row buckets with GROUPED writes.
// Block owns a contiguous edge chunk: LDS histogram -> one global cursor
// claim per (block,bucket) (~100k atomics total) -> grouped stores in runs
// of ~chunk/NB edges (line-dense vs 800k scattered touches).  Entry:
// word0 = col | rowLocal<<16 (needs N <= 65536), word1 = fp32 val.
// Slots beyond CAPB spill to olist (sized E -> unconditionally correct).
// ---------------------------------------------------------------------------
__global__ __launch_bounds__(256) void afill(
        const int* __restrict__ arow, const int* __restrict__ acol,
        const float* __restrict__ aval, int* __restrict__ pcur,
        int* __restrict__ ocount, uint4* __restrict__ olist,
        uint2* __restrict__ payload, int E, int NB, int chunk) {
    __shared__ int cnt[1024];
    __shared__ int base[1024];
    const int t = threadIdx.x;
    const int lo = blockIdx.x * chunk;
    const int hi = min(E, lo + chunk);
    if (lo >= hi) return;
    for (int i = t; i < NB; i += 256) cnt[i] = 0;
    __syncthreads();
    for (int e = lo + t; e < hi; e += 256)
        atomicAdd(&cnt[arow[e] >> RBSH], 1);
    __syncthreads();
    for (int i = t; i < NB; i += 256) {
        const int c = cnt[i];
        base[i] = c ? atomicAdd(&pcur[i], c) : 0;
        cnt[i] = 0;
    }
    __syncthreads();
    for (int e = lo + t; e < hi; e += 256) {
        const int r = arow[e];
        const int b = r >> RBSH;
        const int slot = base[b] + atomicAdd(&cnt[b], 1);
        const unsigned w0 = (unsigned)acol[e] | ((unsigned)(r & (RB - 1)) << 16);
        const unsigned w1 = __float_as_uint(aval[e]);
        if (slot < CAPB) {
            payload[(size_t)b * CAPB + slot] = make_uint2(w0, w1);
        } else {
            const int oi = atomicAdd(ocount, 1);   // olist sized E: always fits
            olist[oi] = make_uint4((unsigned)r, (unsigned)acol[e], w1, 0u);
        }
    }
}

// ---------------------------------------------------------------------------
// bagg3: block b owns rows [64b, 64b+64).  Reads exactly its bucket once:
// int-LDS counting sort by local row (native ds_add_u32), then wave wv
// pulls rows [8wv, 8wv+8) into registers with 4-edge-ILP coalesced 256 B
// xw gathers.  Fused ReLU store.  No fp32 atomics anywhere.
// ---------------------------------------------------------------------------
__global__ __launch_bounds__(512) void bagg3(
        const int* __restrict__ pcur, const uint2* __restrict__ payload,
        const float* __restrict__ xw, float* __restrict__ out, int N,
        const int* __restrict__ ocount, const uint4* __restrict__ olist) {
    __shared__ uint2 stage[CAPB];       // 10 KB
    __shared__ int bins[RB + 1];
    __shared__ int pl[RB];
    const int t = threadIdx.x;
    const int lane = t & 63;
    const int wv = t >> 6;              // 0..7
    const int b = blockIdx.x;
    const int r0 = b << RBSH;

    const int cnt = min(pcur[b], CAPB); // payload filled contiguously [0,cnt)
    if (t <= RB) bins[t] = 0;
    if (t < RB) pl[t] = 0;
    __syncthreads();

    const uint2* pay = payload + (size_t)b * CAPB;
    for (int i = t; i < cnt; i += 512)
        atomicAdd(&bins[(pay[i].x >> 16) & (RB - 1)], 1);
    __syncthreads();
    if (t == 0) {                       // exclusive scan of 64 bins
        int run = 0;
        for (int i = 0; i < RB; ++i) { int v = bins[i]; bins[i] = run; run += v; }
        bins[RB] = run;
    }
    __syncthreads();
    for (int i = t; i < cnt; i += 512) {
        const uint2 e = pay[i];
        const int rl = (e.x >> 16) & (RB - 1);
        stage[bins[rl] + atomicAdd(&pl[rl], 1)] = e;
    }
    __syncthreads();

    float acc[8];
#pragma unroll
    for (int lr = 0; lr < 8; ++lr) {
        const int row = wv * 8 + lr;
        int j = bins[row];
        const int end = bins[row + 1];
        float a = 0.f;
        for (; j + 4 <= end; j += 4) {
            uint2 e0 = stage[j], e1 = stage[j+1], e2 = stage[j+2], e3 = stage[j+3];
            float g0 = xw[(size_t)(e0.x & 0xFFFF) * OUT_DIM + lane];
            float g1 = xw[(size_t)(e1.x & 0xFFFF) * OUT_DIM + lane];
            float g2 = xw[(size_t)(e2.x & 0xFFFF) * OUT_DIM + lane];
            float g3 = xw[(size_t)(e3.x & 0xFFFF) * OUT_DIM + lane];
            a = fmaf(__uint_as_float(e0.y), g0, a);
            a = fmaf(__uint_as_float(e1.y), g1, a);
            a = fmaf(__uint_as_float(e2.y), g2, a);
            a = fmaf(__uint_as_float(e3.y), g3, a);
        }
        for (; j < end; ++j) {
            uint2 e0 = stage[j];
            a = fmaf(__uint_as_float(e0.y),
                     xw[(size_t)(e0.x & 0xFFFF) * OUT_DIM + lane], a);
        }
        acc[lr] = a;
    }

    // overflow contributions (oc == 0 in practice; one uniform load)
    const int oc = *ocount;
    for (int i = 0; i < oc; ++i) {
        const uint4 e = olist[i];
        const int lr = (int)e.x - r0 - wv * 8;
        if (lr >= 0 && lr < 8)
            acc[lr] += __uint_as_float(e.z) * xw[(size_t)e.y * OUT_DIM + lane];
    }

#pragma unroll
    for (int lr = 0; lr < 8; ++lr) {
        const int row = r0 + wv * 8 + lr;
        if (row < N) {
            const float v = acc[lr];
            out[(size_t)row * OUT_DIM + lane] = v > 0.f ? v : 0.f;
        }
    }
}

// ---------------------------------------------------------------------------
// Fallback: gemm + atomic scatter + relu (always correct).
// ---------------------------------------------------------------------------
__global__ __launch_bounds__(256) void scatter_edges(
        const int* __restrict__ arow, const int* __restrict__ acol,
        const float* __restrict__ aval, const float* __restrict__ xw,
        float* __restrict__ out, int E) {
    const int lane = threadIdx.x & 63;
    int gw = (blockIdx.x * 256 + (int)threadIdx.x) >> 6;
    const int nw = (gridDim.x * 256) >> 6;
    for (int e = gw; e < E; e += nw) {
        const float m = aval[e] * xw[(size_t)acol[e] * OUT_DIM + lane];
        atomicAdd(&out[(size_t)arow[e] * OUT_DIM + lane], m);
    }
}

__global__ __launch_bounds__(256) void relu_inplace(float* __restrict__ o, int n4) {
    float4* p = (float4*)o;
    int i = blockIdx.x * 256 + threadIdx.x;
    const int stride = gridDim.x * 256;
    for (; i < n4; i += stride) {
        float4 v = p[i];
        v.x = v.x > 0.f ? v.x : 0.f;
        v.y = v.y > 0.f ? v.y : 0.f;
        v.z = v.z > 0.f ? v.z : 0.f;
        v.w = v.w > 0.f ? v.w : 0.f;
        p[i] = v;
    }
}

static inline size_t align256(size_t x) { return (x + 255) & ~(size_t)255; }

extern "C" void kernel_launch(void* const* d_in, const int* in_sizes, int n_in,
                              void* d_out, int out_size, void* d_ws, size_t ws_size,
                              hipStream_t stream) {
    const float* x    = (const float*)d_in[0];
    const float* w    = (const float*)d_in[1];
    const int*   arow = (const int*)d_in[2];
    const int*   acol = (const int*)d_in[3];
    const float* aval = (const float*)d_in[4];
    float*       out  = (float*)d_out;

    const int N  = in_sizes[0] / IN_DIM;   // 50000
    const int E  = in_sizes[2];            // 800000
    const int NB = (N + RB - 1) >> RBSH;   // 782
    const int GB = (N + 63) / 64;          // gemm blocks

    char* ws = (char*)d_ws;
    const size_t szXW  = align256((size_t)N * OUT_DIM * sizeof(float));
    const size_t szCnt = align256((size_t)(NB + 1) * sizeof(int));   // pcur + ocount
    const size_t szOl  = align256((size_t)E * sizeof(uint4));        // olist sized E
    const size_t szPay = (size_t)NB * CAPB * sizeof(uint2);
    const size_t need0 = szXW + szCnt + szOl + szPay;

    float* xw      = (float*)ws;
    int*   pcur    = (int*)(ws + szXW);
    int*   ocount  = pcur + NB;
    uint4* olist   = (uint4*)(ws + szXW + szCnt);
    uint2* payload = (uint2*)(ws + szXW + szCnt + szOl);

    if (ws_size >= need0 && N <= 65536 && NB <= 1024) {
        (void)hipMemsetAsync(pcur, 0, (size_t)(NB + 1) * sizeof(int), stream);
        gemm_only<<<GB, 256, 0, stream>>>(x, w, xw, N);
        const int chunk = (E + AB2 - 1) / AB2;
        afill<<<AB2, 256, 0, stream>>>(arow, acol, aval, pcur, ocount, olist,
                                       payload, E, NB, chunk);
        bagg3<<<NB, 512, 0, stream>>>(pcur, payload, xw, out, N, ocount, olist);
    } else {
        gemm_only<<<GB, 256, 0, stream>>>(x, w, xw, N);
        (void)hipMemsetAsync(d_out, 0, (size_t)out_size * sizeof(float), stream);
        scatter_edges<<<4096, 256, 0, stream>>>(arow, acol, aval, xw, out, E);
        relu_inplace<<<2048, 256, 0, stream>>>(out, out_size / 4);
    }
}

// Round 12
// 143.564 us; speedup vs baseline: 1.6611x; 1.0235x over previous
//
#include <hip/hip_runtime.h>

#define IN_DIM 128
#define OUT_DIM 64
#define PADK 136     // gemm LDS row stride (bf16 elems)
#define RB 64        // rows per bucket
#define RBSH 6       // log2(RB)
#define CAPB 1280    // bucket capacity (mean 1024, sigma 32 -> +8 sigma)
#define AB2 128      // afill blocks

typedef float f32x4 __attribute__((ext_vector_type(4)));
typedef short bf16x8 __attribute__((ext_vector_type(8)));

__device__ __forceinline__ unsigned short f2bf(float f) {   // RNE f32->bf16
    unsigned u = __float_as_uint(f);
    return (unsigned short)((u + 0x7FFFu + ((u >> 16) & 1u)) >> 16);
}
__device__ __forceinline__ float bf2f(unsigned short h) {
    return __uint_as_float((unsigned)h << 16);
}

// ---------------------------------------------------------------------------
// GEMM: xw(bf16) = x@W via split-bf16 MFMA (hi*hi + hi*lo + lo*hi),
// 64 rows/block.  xw stored bf16: halves gemm write traffic AND bagg3's
// gather line-touches (xw 6.4 MB ~ L2-resident).
// ---------------------------------------------------------------------------
__device__ __forceinline__ void gemm_body(const float* __restrict__ x,
                                          const float* __restrict__ w,
                                          unsigned short* __restrict__ xwb,
                                          int N, int blk) {
    __shared__ unsigned short Ahi[64 * PADK];
    __shared__ unsigned short Alo[64 * PADK];
    __shared__ unsigned short Bhi[64 * PADK];   // W^T: [c][k]
    __shared__ unsigned short Blo[64 * PADK];

    const int t = threadIdx.x;
    const int r0 = blk * 64;

    {   // stage W^T hi/lo
        const int c = t >> 2;
        const int kb = (t & 3) * 32;
        for (int k4 = 0; k4 < 32; k4 += 4) {
            ushort4 h, l;
            float v0 = w[(kb + k4 + 0) * OUT_DIM + c];
            float v1 = w[(kb + k4 + 1) * OUT_DIM + c];
            float v2 = w[(kb + k4 + 2) * OUT_DIM + c];
            float v3 = w[(kb + k4 + 3) * OUT_DIM + c];
            h.x = f2bf(v0); l.x = f2bf(v0 - bf2f(h.x));
            h.y = f2bf(v1); l.y = f2bf(v1 - bf2f(h.y));
            h.z = f2bf(v2); l.z = f2bf(v2 - bf2f(h.z));
            h.w = f2bf(v3); l.w = f2bf(v3 - bf2f(h.w));
            *(ushort4*)&Bhi[c * PADK + kb + k4] = h;
            *(ushort4*)&Blo[c * PADK + kb + k4] = l;
        }
    }
    {   // stage x rows hi/lo
        const float4* x4 = (const float4*)x;
        for (int i = 0; i < 8; ++i) {
            const int f = i * 256 + t;
            const int rr = f >> 5;
            const int kk = (f & 31) * 4;
            int row = r0 + rr; if (row >= N) row = N - 1;
            float4 v = x4[(size_t)row * (IN_DIM / 4) + (kk >> 2)];
            ushort4 h, l;
            h.x = f2bf(v.x); l.x = f2bf(v.x - bf2f(h.x));
            h.y = f2bf(v.y); l.y = f2bf(v.y - bf2f(h.y));
            h.z = f2bf(v.z); l.z = f2bf(v.z - bf2f(h.z));
            h.w = f2bf(v.w); l.w = f2bf(v.w - bf2f(h.w));
            *(ushort4*)&Ahi[rr * PADK + kk] = h;
            *(ushort4*)&Alo[rr * PADK + kk] = l;
        }
    }
    __syncthreads();

    const int lane = t & 63;
    const int wv = t >> 6;
    const int m = lane & 15;
    const int quad = lane >> 4;

    bf16x8 ahi[4], alo[4];
#pragma unroll
    for (int ks = 0; ks < 4; ++ks) {
        const int off = (wv * 16 + m) * PADK + ks * 32 + quad * 8;
        ahi[ks] = *(const bf16x8*)&Ahi[off];
        alo[ks] = *(const bf16x8*)&Alo[off];
    }
#pragma unroll
    for (int ct = 0; ct < 4; ++ct) {
        f32x4 acc = {0.f, 0.f, 0.f, 0.f};
#pragma unroll
        for (int ks = 0; ks < 4; ++ks) {
            const int off = (ct * 16 + m) * PADK + ks * 32 + quad * 8;
            bf16x8 bh = *(const bf16x8*)&Bhi[off];
            bf16x8 bl = *(const bf16x8*)&Blo[off];
            acc = __builtin_amdgcn_mfma_f32_16x16x32_bf16(alo[ks], bh, acc, 0, 0, 0);
            acc = __builtin_amdgcn_mfma_f32_16x16x32_bf16(ahi[ks], bl, acc, 0, 0, 0);
            acc = __builtin_amdgcn_mfma_f32_16x16x32_bf16(ahi[ks], bh, acc, 0, 0, 0);
        }
#pragma unroll
        for (int i = 0; i < 4; ++i) {
            const int row = r0 + wv * 16 + quad * 4 + i;
            if (row < N) xwb[(size_t)row * OUT_DIM + ct * 16 + m] = f2bf(acc[i]);
        }
    }
}

__global__ __launch_bounds__(256) void gemm_only(const float* __restrict__ x,
                                                 const float* __restrict__ w,
                                                 unsigned short* __restrict__ xwb,
                                                 int N) {
    gemm_body(x, w, xwb, N, blockIdx.x);
}

// ---------------------------------------------------------------------------
// afill: bin edges into fixed-capacity 64-row buckets with GROUPED writes.
// LDS histogram -> one global cursor claim per (block,bucket) -> grouped
// stores in ~8-edge/64 B runs.  word0 = col | rowLocal<<16 (N <= 65536),
// word1 = fp32 val.  Slots beyond CAPB spill to olist (sized E -> airtight).
// ---------------------------------------------------------------------------
__global__ __launch_bounds__(256) void afill(
        const int* __restrict__ arow, const int* __restrict__ acol,
        const float* __restrict__ aval, int* __restrict__ pcur,
        int* __restrict__ ocount, uint4* __restrict__ olist,
        uint2* __restrict__ payload, int E, int NB, int chunk) {
    __shared__ int cnt[1024];
    __shared__ int base[1024];
    const int t = threadIdx.x;
    const int lo = blockIdx.x * chunk;
    const int hi = min(E, lo + chunk);
    if (lo >= hi) return;
    for (int i = t; i < NB; i += 256) cnt[i] = 0;
    __syncthreads();
    for (int e = lo + t; e < hi; e += 256)
        atomicAdd(&cnt[arow[e] >> RBSH], 1);
    __syncthreads();
    for (int i = t; i < NB; i += 256) {
        const int c = cnt[i];
        base[i] = c ? atomicAdd(&pcur[i], c) : 0;
        cnt[i] = 0;
    }
    __syncthreads();
    for (int e = lo + t; e < hi; e += 256) {
        const int r = arow[e];
        const int b = r >> RBSH;
        const int slot = base[b] + atomicAdd(&cnt[b], 1);
        const unsigned w0 = (unsigned)acol[e] | ((unsigned)(r & (RB - 1)) << 16);
        const unsigned w1 = __float_as_uint(aval[e]);
        if (slot < CAPB) {
            payload[(size_t)b * CAPB + slot] = make_uint2(w0, w1);
        } else {
            const int oi = atomicAdd(ocount, 1);   // olist sized E: always fits
            olist[oi] = make_uint4((unsigned)r, (unsigned)acol[e], w1, 0u);
        }
    }
}

// ---------------------------------------------------------------------------
// bagg3: block b owns rows [64b, 64b+64).  Int-LDS counting sort by local
// row, then wave wv pulls rows [8wv, 8wv+8) into registers with 4-edge-ILP
// coalesced 128 B bf16 xw gathers.  Fused ReLU store.  No fp32 atomics.
// ---------------------------------------------------------------------------
__global__ __launch_bounds__(512) void bagg3(
        const int* __restrict__ pcur, const uint2* __restrict__ payload,
        const unsigned short* __restrict__ xwb, float* __restrict__ out, int N,
        const int* __restrict__ ocount, const uint4* __restrict__ olist) {
    __shared__ uint2 stage[CAPB];       // 10 KB
    __shared__ int bins[RB + 1];
    __shared__ int pl[RB];
    const int t = threadIdx.x;
    const int lane = t & 63;
    const int wv = t >> 6;              // 0..7
    const int b = blockIdx.x;
    const int r0 = b << RBSH;

    const int cnt = min(pcur[b], CAPB); // payload filled contiguously [0,cnt)
    if (t <= RB) bins[t] = 0;
    if (t < RB) pl[t] = 0;
    __syncthreads();

    const uint2* pay = payload + (size_t)b * CAPB;
    for (int i = t; i < cnt; i += 512)
        atomicAdd(&bins[(pay[i].x >> 16) & (RB - 1)], 1);
    __syncthreads();
    if (t == 0) {                       // exclusive scan of 64 bins
        int run = 0;
        for (int i = 0; i < RB; ++i) { int v = bins[i]; bins[i] = run; run += v; }
        bins[RB] = run;
    }
    __syncthreads();
    for (int i = t; i < cnt; i += 512) {
        const uint2 e = pay[i];
        const int rl = (e.x >> 16) & (RB - 1);
        stage[bins[rl] + atomicAdd(&pl[rl], 1)] = e;
    }
    __syncthreads();

    float acc[8];
#pragma unroll
    for (int lr = 0; lr < 8; ++lr) {
        const int row = wv * 8 + lr;
        int j = bins[row];
        const int end = bins[row + 1];
        float a = 0.f;
        for (; j + 4 <= end; j += 4) {
            uint2 e0 = stage[j], e1 = stage[j+1], e2 = stage[j+2], e3 = stage[j+3];
            float g0 = bf2f(xwb[(size_t)(e0.x & 0xFFFF) * OUT_DIM + lane]);
            float g1 = bf2f(xwb[(size_t)(e1.x & 0xFFFF) * OUT_DIM + lane]);
            float g2 = bf2f(xwb[(size_t)(e2.x & 0xFFFF) * OUT_DIM + lane]);
            float g3 = bf2f(xwb[(size_t)(e3.x & 0xFFFF) * OUT_DIM + lane]);
            a = fmaf(__uint_as_float(e0.y), g0, a);
            a = fmaf(__uint_as_float(e1.y), g1, a);
            a = fmaf(__uint_as_float(e2.y), g2, a);
            a = fmaf(__uint_as_float(e3.y), g3, a);
        }
        for (; j < end; ++j) {
            uint2 e0 = stage[j];
            a = fmaf(__uint_as_float(e0.y),
                     bf2f(xwb[(size_t)(e0.x & 0xFFFF) * OUT_DIM + lane]), a);
        }
        acc[lr] = a;
    }

    // overflow contributions (oc == 0 in practice; one uniform load)
    const int oc = *ocount;
    for (int i = 0; i < oc; ++i) {
        const uint4 e = olist[i];
        const int lr = (int)e.x - r0 - wv * 8;
        if (lr >= 0 && lr < 8)
            acc[lr] += __uint_as_float(e.z) *
                       bf2f(xwb[(size_t)e.y * OUT_DIM + lane]);
    }

#pragma unroll
    for (int lr = 0; lr < 8; ++lr) {
        const int row = r0 + wv * 8 + lr;
        if (row < N) {
            const float v = acc[lr];
            out[(size_t)row * OUT_DIM + lane] = v > 0.f ? v : 0.f;
        }
    }
}

// ---------------------------------------------------------------------------
// Fallback: gemm + atomic scatter + relu (always correct).
// ---------------------------------------------------------------------------
__global__ __launch_bounds__(256) void scatter_edges(
        const int* __restrict__ arow, const int* __restrict__ acol,
        const float* __restrict__ aval, const unsigned short* __restrict__ xwb,
        float* __restrict__ out, int E) {
    const int lane = threadIdx.x & 63;
    int gw = (blockIdx.x * 256 + (int)threadIdx.x) >> 6;
    const int nw = (gridDim.x * 256) >> 6;
    for (int e = gw; e < E; e += nw) {
        const float m = aval[e] * bf2f(xwb[(size_t)acol[e] * OUT_DIM + lane]);
        atomicAdd(&out[(size_t)arow[e] * OUT_DIM + lane], m);
    }
}

__global__ __launch_bounds__(256) void relu_inplace(float* __restrict__ o, int n4) {
    float4* p = (float4*)o;
    int i = blockIdx.x * 256 + threadIdx.x;
    const int stride = gridDim.x * 256;
    for (; i < n4; i += stride) {
        float4 v = p[i];
        v.x = v.x > 0.f ? v.x : 0.f;
        v.y = v.y > 0.f ? v.y : 0.f;
        v.z = v.z > 0.f ? v.z : 0.f;
        v.w = v.w > 0.f ? v.w : 0.f;
        p[i] = v;
    }
}

static inline size_t align256(size_t x) { return (x + 255) & ~(size_t)255; }

extern "C" void kernel_launch(void* const* d_in, const int* in_sizes, int n_in,
                              void* d_out, int out_size, void* d_ws, size_t ws_size,
                              hipStream_t stream) {
    const float* x    = (const float*)d_in[0];
    const float* w    = (const float*)d_in[1];
    const int*   arow = (const int*)d_in[2];
    const int*   acol = (const int*)d_in[3];
    const float* aval = (const float*)d_in[4];
    float*       out  = (float*)d_out;

    const int N  = in_sizes[0] / IN_DIM;   // 50000
    const int E  = in_sizes[2];            // 800000
    const int NB = (N + RB - 1) >> RBSH;   // 782
    const int GB = (N + 63) / 64;          // gemm blocks

    char* ws = (char*)d_ws;
    const size_t szXW  = align256((size_t)N * OUT_DIM * sizeof(unsigned short));
    const size_t szCnt = align256((size_t)(NB + 1) * sizeof(int));   // pcur + ocount
    const size_t szOl  = align256((size_t)E * sizeof(uint4));        // olist sized E
    const size_t szPay = (size_t)NB * CAPB * sizeof(uint2);
    const size_t need0 = szXW + szCnt + szOl + szPay;

    unsigned short* xwb = (unsigned short*)ws;
    int*   pcur    = (int*)(ws + szXW);
    int*   ocount  = pcur + NB;
    uint4* olist   = (uint4*)(ws + szXW + szCnt);
    uint2* payload = (uint2*)(ws + szXW + szCnt + szOl);

    if (ws_size >= need0 && N <= 65536 && NB <= 1024) {
        (void)hipMemsetAsync(pcur, 0, (size_t)(NB + 1) * sizeof(int), stream);
        gemm_only<<<GB, 256, 0, stream>>>(x, w, xwb, N);
        const int chunk = (E + AB2 - 1) / AB2;
        afill<<<AB2, 256, 0, stream>>>(arow, acol, aval, pcur, ocount, olist,
                                       payload, E, NB, chunk);
        bagg3<<<NB, 512, 0, stream>>>(pcur, payload, xwb, out, N, ocount, olist);
    } else {
        gemm_only<<<GB, 256, 0, stream>>>(x, w, xwb, N);
        (void)hipMemsetAsync(d_out, 0, (size_t)out_size * sizeof(float), stream);
        scatter_edges<<<4096, 256, 0, stream>>>(arow, acol, aval, xwb, out, E);
        relu_inplace<<<2048, 256, 0, stream>>>(out, out_size / 4);
    }
}

// Round 13
// 131.770 us; speedup vs baseline: 1.8098x; 1.0895x over previous
//
#include <hip/hip_runtime.h>

#define IN_DIM 128
#define OUT_DIM 64
#define PADK 136     // gemm LDS row stride (bf16 elems)
#define RB 64        // rows per bucket
#define RBSH 6       // log2(RB)
#define CAPB 1280    // bucket capacity (mean 1024, sigma 32 -> +8 sigma)
#define AB2 128      // afill blocks (fused: <= 1 per CU, overlap with gemm)

typedef float f32x4 __attribute__((ext_vector_type(4)));
typedef short bf16x8 __attribute__((ext_vector_type(8)));

__device__ __forceinline__ unsigned short f2bf(float f) {   // RNE f32->bf16
    unsigned u = __float_as_uint(f);
    return (unsigned short)((u + 0x7FFFu + ((u >> 16) & 1u)) >> 16);
}
__device__ __forceinline__ float bf2f(unsigned short h) {
    return __uint_as_float((unsigned)h << 16);
}

// ---------------------------------------------------------------------------
// GEMM body: xw(bf16) = x@W via split-bf16 MFMA (hi*hi + hi*lo + lo*hi),
// 64 rows/block.  LDS passed in (aliased with afill branch in fused kernel).
// ---------------------------------------------------------------------------
__device__ __forceinline__ void gemm_body(const float* __restrict__ x,
                                          const float* __restrict__ w,
                                          unsigned short* __restrict__ xwb,
                                          int N, int blk,
                                          unsigned short* lds) {
    unsigned short* Ahi = lds;                 // 4 x 17 KB = 68 KB total
    unsigned short* Alo = lds + 64 * PADK;
    unsigned short* Bhi = lds + 2 * 64 * PADK; // W^T: [c][k]
    unsigned short* Blo = lds + 3 * 64 * PADK;

    const int t = threadIdx.x;
    const int r0 = blk * 64;

    {   // stage W^T hi/lo
        const int c = t >> 2;
        const int kb = (t & 3) * 32;
        for (int k4 = 0; k4 < 32; k4 += 4) {
            ushort4 h, l;
            float v0 = w[(kb + k4 + 0) * OUT_DIM + c];
            float v1 = w[(kb + k4 + 1) * OUT_DIM + c];
            float v2 = w[(kb + k4 + 2) * OUT_DIM + c];
            float v3 = w[(kb + k4 + 3) * OUT_DIM + c];
            h.x = f2bf(v0); l.x = f2bf(v0 - bf2f(h.x));
            h.y = f2bf(v1); l.y = f2bf(v1 - bf2f(h.y));
            h.z = f2bf(v2); l.z = f2bf(v2 - bf2f(h.z));
            h.w = f2bf(v3); l.w = f2bf(v3 - bf2f(h.w));
            *(ushort4*)&Bhi[c * PADK + kb + k4] = h;
            *(ushort4*)&Blo[c * PADK + kb + k4] = l;
        }
    }
    {   // stage x rows hi/lo
        const float4* x4 = (const float4*)x;
        for (int i = 0; i < 8; ++i) {
            const int f = i * 256 + t;
            const int rr = f >> 5;
            const int kk = (f & 31) * 4;
            int row = r0 + rr; if (row >= N) row = N - 1;
            float4 v = x4[(size_t)row * (IN_DIM / 4) + (kk >> 2)];
            ushort4 h, l;
            h.x = f2bf(v.x); l.x = f2bf(v.x - bf2f(h.x));
            h.y = f2bf(v.y); l.y = f2bf(v.y - bf2f(h.y));
            h.z = f2bf(v.z); l.z = f2bf(v.z - bf2f(h.z));
            h.w = f2bf(v.w); l.w = f2bf(v.w - bf2f(h.w));
            *(ushort4*)&Ahi[rr * PADK + kk] = h;
            *(ushort4*)&Alo[rr * PADK + kk] = l;
        }
    }
    __syncthreads();

    const int lane = t & 63;
    const int wv = t >> 6;
    const int m = lane & 15;
    const int quad = lane >> 4;

    bf16x8 ahi[4], alo[4];
#pragma unroll
    for (int ks = 0; ks < 4; ++ks) {
        const int off = (wv * 16 + m) * PADK + ks * 32 + quad * 8;
        ahi[ks] = *(const bf16x8*)&Ahi[off];
        alo[ks] = *(const bf16x8*)&Alo[off];
    }
#pragma unroll
    for (int ct = 0; ct < 4; ++ct) {
        f32x4 acc = {0.f, 0.f, 0.f, 0.f};
#pragma unroll
        for (int ks = 0; ks < 4; ++ks) {
            const int off = (ct * 16 + m) * PADK + ks * 32 + quad * 8;
            bf16x8 bh = *(const bf16x8*)&Bhi[off];
            bf16x8 bl = *(const bf16x8*)&Blo[off];
            acc = __builtin_amdgcn_mfma_f32_16x16x32_bf16(alo[ks], bh, acc, 0, 0, 0);
            acc = __builtin_amdgcn_mfma_f32_16x16x32_bf16(ahi[ks], bl, acc, 0, 0, 0);
            acc = __builtin_amdgcn_mfma_f32_16x16x32_bf16(ahi[ks], bh, acc, 0, 0, 0);
        }
#pragma unroll
        for (int i = 0; i < 4; ++i) {
            const int row = r0 + wv * 16 + quad * 4 + i;
            if (row < N) xwb[(size_t)row * OUT_DIM + ct * 16 + m] = f2bf(acc[i]);
        }
    }
}

// ---------------------------------------------------------------------------
// afill body: bin edges into fixed-capacity 64-row buckets, GROUPED writes.
// LDS histogram -> one global cursor claim per (block,bucket) -> grouped
// stores in ~8-edge/64 B runs.  word0 = col | rowLocal<<16 (N <= 65536),
// word1 = fp32 val.  Slots beyond CAPB spill to olist (sized E: airtight).
// ---------------------------------------------------------------------------
__device__ __forceinline__ void afill_body(
        const int* __restrict__ arow, const int* __restrict__ acol,
        const float* __restrict__ aval, int* __restrict__ pcur,
        int* __restrict__ ocount, uint4* __restrict__ olist,
        uint2* __restrict__ payload, int E, int NB, int chunk, int blk,
        int* ldsi) {
    int* cnt  = ldsi;          // [1024]
    int* base = ldsi + 1024;   // [1024]   (8 KB total, aliased into gemm LDS)
    const int t = threadIdx.x;
    const int lo = blk * chunk;
    const int hi = min(E, lo + chunk);
    if (lo >= hi) return;
    for (int i = t; i < NB; i += 256) cnt[i] = 0;
    __syncthreads();
    for (int e = lo + t; e < hi; e += 256)
        atomicAdd(&cnt[arow[e] >> RBSH], 1);
    __syncthreads();
    for (int i = t; i < NB; i += 256) {
        const int c = cnt[i];
        base[i] = c ? atomicAdd(&pcur[i], c) : 0;
        cnt[i] = 0;
    }
    __syncthreads();
    for (int e = lo + t; e < hi; e += 256) {
        const int r = arow[e];
        const int b = r >> RBSH;
        const int slot = base[b] + atomicAdd(&cnt[b], 1);
        const unsigned w0 = (unsigned)acol[e] | ((unsigned)(r & (RB - 1)) << 16);
        const unsigned w1 = __float_as_uint(aval[e]);
        if (slot < CAPB) {
            payload[(size_t)b * CAPB + slot] = make_uint2(w0, w1);
        } else {
            const int oi = atomicAdd(ocount, 1);   // olist sized E: always fits
            olist[oi] = make_uint4((unsigned)r, (unsigned)acol[e], w1, 0u);
        }
    }
}

// ---------------------------------------------------------------------------
// K1 fused: blocks [0,AB2) run afill (first in grid -> scheduling round 0,
// overlaps the gemm); blocks [AB2, AB2+GB) run the GEMM.  afill's 8 KB LDS
// is aliased into the gemm's 68 KB buffer (branch-disjoint), so the LDS
// footprint stays 69632 and afill costs no extra occupancy (R10 lesson).
// ---------------------------------------------------------------------------
__global__ __launch_bounds__(256) void gemm_afill(
        const float* __restrict__ x, const float* __restrict__ w,
        unsigned short* __restrict__ xwb, int N,
        const int* __restrict__ arow, const int* __restrict__ acol,
        const float* __restrict__ aval, int* __restrict__ pcur,
        int* __restrict__ ocount, uint4* __restrict__ olist,
        uint2* __restrict__ payload, int E, int NB, int chunk) {
    __shared__ unsigned short LB[4 * 64 * PADK];   // 68 KB, shared by branches
    if ((int)blockIdx.x < AB2) {
        afill_body(arow, acol, aval, pcur, ocount, olist, payload, E, NB,
                   chunk, blockIdx.x, (int*)LB);
    } else {
        gemm_body(x, w, xwb, N, blockIdx.x - AB2, LB);
    }
}

__global__ __launch_bounds__(256) void gemm_only(const float* __restrict__ x,
                                                 const float* __restrict__ w,
                                                 unsigned short* __restrict__ xwb,
                                                 int N) {
    __shared__ unsigned short LB[4 * 64 * PADK];
    gemm_body(x, w, xwb, N, blockIdx.x, LB);
}

// ---------------------------------------------------------------------------
// bagg3: block b owns rows [64b, 64b+64).  Int-LDS counting sort by local
// row, then wave wv pulls rows [8wv, 8wv+8) into registers with 8-edge-ILP
// coalesced 128 B bf16 xw gathers (latency-bound -> max MLP).  Fused ReLU.
// ---------------------------------------------------------------------------
__global__ __launch_bounds__(512) void bagg3(
        const int* __restrict__ pcur, const uint2* __restrict__ payload,
        const unsigned short* __restrict__ xwb, float* __restrict__ out, int N,
        const int* __restrict__ ocount, const uint4* __restrict__ olist) {
    __shared__ uint2 stage[CAPB];       // 10 KB
    __shared__ int bins[RB + 1];
    __shared__ int pl[RB];
    const int t = threadIdx.x;
    const int lane = t & 63;
    const int wv = t >> 6;              // 0..7
    const int b = blockIdx.x;
    const int r0 = b << RBSH;

    const int cnt = min(pcur[b], CAPB); // payload filled contiguously [0,cnt)
    if (t <= RB) bins[t] = 0;
    if (t < RB) pl[t] = 0;
    __syncthreads();

    const uint2* pay = payload + (size_t)b * CAPB;
    for (int i = t; i < cnt; i += 512)
        atomicAdd(&bins[(pay[i].x >> 16) & (RB - 1)], 1);
    __syncthreads();
    if (t == 0) {                       // exclusive scan of 64 bins
        int run = 0;
        for (int i = 0; i < RB; ++i) { int v = bins[i]; bins[i] = run; run += v; }
        bins[RB] = run;
    }
    __syncthreads();
    for (int i = t; i < cnt; i += 512) {
        const uint2 e = pay[i];
        const int rl = (e.x >> 16) & (RB - 1);
        stage[bins[rl] + atomicAdd(&pl[rl], 1)] = e;
    }
    __syncthreads();

    float acc[8];
#pragma unroll
    for (int lr = 0; lr < 8; ++lr) {
        const int row = wv * 8 + lr;
        int j = bins[row];
        const int end = bins[row + 1];
        float a0 = 0.f, a1 = 0.f;
        for (; j + 8 <= end; j += 8) {
            uint2 e0 = stage[j],   e1 = stage[j+1], e2 = stage[j+2], e3 = stage[j+3];
            uint2 e4 = stage[j+4], e5 = stage[j+5], e6 = stage[j+6], e7 = stage[j+7];
            float g0 = bf2f(xwb[(size_t)(e0.x & 0xFFFF) * OUT_DIM + lane]);
            float g1 = bf2f(xwb[(size_t)(e1.x & 0xFFFF) * OUT_DIM + lane]);
            float g2 = bf2f(xwb[(size_t)(e2.x & 0xFFFF) * OUT_DIM + lane]);
            float g3 = bf2f(xwb[(size_t)(e3.x & 0xFFFF) * OUT_DIM + lane]);
            float g4 = bf2f(xwb[(size_t)(e4.x & 0xFFFF) * OUT_DIM + lane]);
            float g5 = bf2f(xwb[(size_t)(e5.x & 0xFFFF) * OUT_DIM + lane]);
            float g6 = bf2f(xwb[(size_t)(e6.x & 0xFFFF) * OUT_DIM + lane]);
            float g7 = bf2f(xwb[(size_t)(e7.x & 0xFFFF) * OUT_DIM + lane]);
            a0 = fmaf(__uint_as_float(e0.y), g0, a0);
            a1 = fmaf(__uint_as_float(e1.y), g1, a1);
            a0 = fmaf(__uint_as_float(e2.y), g2, a0);
            a1 = fmaf(__uint_as_float(e3.y), g3, a1);
            a0 = fmaf(__uint_as_float(e4.y), g4, a0);
            a1 = fmaf(__uint_as_float(e5.y), g5, a1);
            a0 = fmaf(__uint_as_float(e6.y), g6, a0);
            a1 = fmaf(__uint_as_float(e7.y), g7, a1);
        }
        for (; j + 4 <= end; j += 4) {
            uint2 e0 = stage[j], e1 = stage[j+1], e2 = stage[j+2], e3 = stage[j+3];
            float g0 = bf2f(xwb[(size_t)(e0.x & 0xFFFF) * OUT_DIM + lane]);
            float g1 = bf2f(xwb[(size_t)(e1.x & 0xFFFF) * OUT_DIM + lane]);
            float g2 = bf2f(xwb[(size_t)(e2.x & 0xFFFF) * OUT_DIM + lane]);
            float g3 = bf2f(xwb[(size_t)(e3.x & 0xFFFF) * OUT_DIM + lane]);
            a0 = fmaf(__uint_as_float(e0.y), g0, a0);
            a1 = fmaf(__uint_as_float(e1.y), g1, a1);
            a0 = fmaf(__uint_as_float(e2.y), g2, a0);
            a1 = fmaf(__uint_as_float(e3.y), g3, a1);
        }
        for (; j < end; ++j) {
            uint2 e0 = stage[j];
            a0 = fmaf(__uint_as_float(e0.y),
                      bf2f(xwb[(size_t)(e0.x & 0xFFFF) * OUT_DIM + lane]), a0);
        }
        acc[lr] = a0 + a1;
    }

    // overflow contributions (oc == 0 in practice; one uniform load)
    const int oc = *ocount;
    for (int i = 0; i < oc; ++i) {
        const uint4 e = olist[i];
        const int lr = (int)e.x - r0 - wv * 8;
        if (lr >= 0 && lr < 8)
            acc[lr] += __uint_as_float(e.z) *
                       bf2f(xwb[(size_t)e.y * OUT_DIM + lane]);
    }

#pragma unroll
    for (int lr = 0; lr < 8; ++lr) {
        const int row = r0 + wv * 8 + lr;
        if (row < N) {
            const float v = acc[lr];
            out[(size_t)row * OUT_DIM + lane] = v > 0.f ? v : 0.f;
        }
    }
}

// ---------------------------------------------------------------------------
// Fallback: gemm + atomic scatter + relu (always correct).
// ---------------------------------------------------------------------------
__global__ __launch_bounds__(256) void scatter_edges(
        const int* __restrict__ arow, const int* __restrict__ acol,
        const float* __restrict__ aval, const unsigned short* __restrict__ xwb,
        float* __restrict__ out, int E) {
    const int lane = threadIdx.x & 63;
    int gw = (blockIdx.x * 256 + (int)threadIdx.x) >> 6;
    const int nw = (gridDim.x * 256) >> 6;
    for (int e = gw; e < E; e += nw) {
        const float m = aval[e] * bf2f(xwb[(size_t)acol[e] * OUT_DIM + lane]);
        atomicAdd(&out[(size_t)arow[e] * OUT_DIM + lane], m);
    }
}

__global__ __launch_bounds__(256) void relu_inplace(float* __restrict__ o, int n4) {
    float4* p = (float4*)o;
    int i = blockIdx.x * 256 + threadIdx.x;
    const int stride = gridDim.x * 256;
    for (; i < n4; i += stride) {
        float4 v = p[i];
        v.x = v.x > 0.f ? v.x : 0.f;
        v.y = v.y > 0.f ? v.y : 0.f;
        v.z = v.z > 0.f ? v.z : 0.f;
        v.w = v.w > 0.f ? v.w : 0.f;
        p[i] = v;
    }
}

static inline size_t align256(size_t x) { return (x + 255) & ~(size_t)255; }

extern "C" void kernel_launch(void* const* d_in, const int* in_sizes, int n_in,
                              void* d_out, int out_size, void* d_ws, size_t ws_size,
                              hipStream_t stream) {
    const float* x    = (const float*)d_in[0];
    const float* w    = (const float*)d_in[1];
    const int*   arow = (const int*)d_in[2];
    const int*   acol = (const int*)d_in[3];
    const float* aval = (const float*)d_in[4];
    float*       out  = (float*)d_out;

    const int N  = in_sizes[0] / IN_DIM;   // 50000
    const int E  = in_sizes[2];            // 800000
    const int NB = (N + RB - 1) >> RBSH;   // 782
    const int GB = (N + 63) / 64;          // gemm blocks

    char* ws = (char*)d_ws;
    const size_t szXW  = align256((size_t)N * OUT_DIM * sizeof(unsigned short));
    const size_t szCnt = align256((size_t)(NB + 1) * sizeof(int));   // pcur + ocount
    const size_t szOl  = align256((size_t)E * sizeof(uint4));        // olist sized E
    const size_t szPay = (size_t)NB * CAPB * sizeof(uint2);
    const size_t need0 = szXW + szCnt + szOl + szPay;

    unsigned short* xwb = (unsigned short*)ws;
    int*   pcur    = (int*)(ws + szXW);
    int*   ocount  = pcur + NB;
    uint4* olist   = (uint4*)(ws + szXW + szCnt);
    uint2* payload = (uint2*)(ws + szXW + szCnt + szOl);

    if (ws_size >= need0 && N <= 65536 && NB <= 1024) {
        (void)hipMemsetAsync(pcur, 0, (size_t)(NB + 1) * sizeof(int), stream);
        const int chunk = (E + AB2 - 1) / AB2;
        gemm_afill<<<AB2 + GB, 256, 0, stream>>>(x, w, xwb, N, arow, acol, aval,
                                                 pcur, ocount, olist, payload,
                                                 E, NB, chunk);
        bagg3<<<NB, 512, 0, stream>>>(pcur, payload, xwb, out, N, ocount, olist);
    } else {
        gemm_only<<<GB, 256, 0, stream>>>(x, w, xwb, N);
        (void)hipMemsetAsync(d_out, 0, (size_t)out_size * sizeof(float), stream);
        scatter_edges<<<4096, 256, 0, stream>>>(arow, acol, aval, xwb, out, E);
        relu_inplace<<<2048, 256, 0, stream>>>(out, out_size / 4);
    }
}